// Round 5
// baseline (205.840 us; speedup 1.0000x reference)
//
#include <hip/hip_runtime.h>
#include <hip/hip_cooperative_groups.h>
#include <stdint.h>

#define N 8192
#define NCLS 80
#define NWD 128             // keep-mask words (8192 bits)
#define PAIR_CAP (1 << 20)  // 1M edges (4 MB); expected E ~ 2K

namespace cg = cooperative_groups;

// Single fused cooperative kernel. Phases separated by grid.sync():
//  P0   argmax class (8 threads/box) + zero counters
//  P0.5 valid-compaction (order-free: edge direction comes from keys)
//  P1   sparse suppression-pair extraction (256x64 tiles, compact space)
//  P2   greedy NMS as sparse Jacobi fixpoint (block 0)
//  P3   outputs
__global__ void __launch_bounds__(256) k_fused(
    const float* __restrict__ box, const float* __restrict__ conf,
    const float* __restrict__ logits,
    int* __restrict__ cls, int* __restrict__ cmap,
    float4* __restrict__ sbx, float* __restrict__ sarea,
    int* __restrict__ scls, unsigned long long* __restrict__ skey,
    int* __restrict__ Vcnt, int* __restrict__ paircnt,
    unsigned int* __restrict__ pairs, unsigned long long* __restrict__ keepw,
    float* __restrict__ out)
{
#pragma clang fp contract(off)
    cg::grid_group grid = cg::this_grid();
    const int tid = threadIdx.x;
    const int bid = blockIdx.x;
    const int gid = bid * 256 + tid;          // 0..65535

    // ---- P0: per-box class argmax, 8 threads per box ----
    if (gid == 0) *Vcnt = 0;
    if (gid == 1) *paircnt = 0;
    {
        int i = gid >> 3, s = gid & 7;
        const float4* lp = (const float4*)(logits + (size_t)i * NCLS);
        float best = -INFINITY; int bi = 0;
#pragma unroll
        for (int k2 = 0; k2 < 3; ++k2) {
            int c4 = s + 8 * k2;              // 20 float4 chunks over 8 lanes
            if (c4 < 20) {
                float4 v = lp[c4]; int b = c4 * 4;
                if (v.x > best) { best = v.x; bi = b; }
                if (v.y > best) { best = v.y; bi = b + 1; }
                if (v.z > best) { best = v.z; bi = b + 2; }
                if (v.w > best) { best = v.w; bi = b + 3; }
            }
        }
        // 8-lane butterfly reduce; ties -> lowest index (jnp first-max)
#pragma unroll
        for (int off = 1; off < 8; off <<= 1) {
            float ob = __shfl_xor(best, off, 8);
            int   oi = __shfl_xor(bi, off, 8);
            if (ob > best || (ob == best && oi < bi)) { best = ob; bi = oi; }
        }
        if (s == 0) cls[i] = bi;
    }
    grid.sync();

    // ---- P0.5: compact valid boxes (arbitrary order) ----
    if (gid < N) {
        float c = conf[gid];
        int cm = -1;
        if (c > 0.5f) {
            int cid = atomicAdd(Vcnt, 1);
            cm = cid;
            float4 b = ((const float4*)box)[gid];     // x, y, w, h
            float hw = b.z * 0.5f, hh = b.w * 0.5f;   // == w/2 exactly
            sbx[cid] = make_float4(b.x - hw, b.y - hh, b.x + hw, b.y + hh);
            sarea[cid] = b.z * b.w;
            scls[cid] = cls[gid];
            // 64-bit key == jnp stable argsort order: asc key <=> desc conf,
            // exact-duplicate conf tie-broken by original index.
            skey[cid] = ((unsigned long long)(unsigned)(~__float_as_uint(c)) << 32)
                        | (unsigned)gid;
        }
        cmap[gid] = cm;
    }
    grid.sync();

    // ---- P1: suppression pairs, 256-row x 64-col tiles, balanced ----
    {
        __shared__ float4 cb[64];
        __shared__ float  ca[64];
        __shared__ int    ci[64];
        __shared__ unsigned long long ck[64];
        int V = *Vcnt;
        int V64 = (V + 63) >> 6;              // active col-blocks
        int R = (V + 255) >> 8;               // active row-blocks
        for (int a0 = bid; ; a0 += 256) {
            // decode a0 -> (ti, tj) over upper-tri tiles: row ti has cols [4ti, V64)
            int rem = a0, ti = 0; bool ok = false;
            for (; ti < R; ++ti) {
                int rl = V64 - 4 * ti;        // >= 1 for ti < R
                if (rem < rl) { ok = true; break; }
                rem -= rl;
            }
            if (!ok) break;                   // uniform exit
            int rbase = ti << 8, cbase = (4 * ti + rem) << 6;
            __syncthreads();                  // LDS reuse guard
            if (tid < 64) {
                int c = cbase + tid;          // < 8192; beyond V is unused garbage
                cb[tid] = sbx[c]; ca[tid] = sarea[c];
                ci[tid] = scls[c]; ck[tid] = skey[c];
            }
            __syncthreads();
            int r = rbase + tid;
            if (r < V) {
                float4 rb = sbx[r];
                float rar = sarea[r];
                int rcls = scls[r];
                unsigned long long rk = skey[r];
                for (int k = 0; k < 64; ++k) {
                    int c = cbase + k;
                    float4 c4 = cb[k];
                    // exact float32 op order of the reference:
                    float iw = fminf(rb.z, c4.z) - fmaxf(rb.x, c4.x);
                    iw = fmaxf(iw, 0.0f);
                    float ih = fminf(rb.w, c4.w) - fmaxf(rb.y, c4.y);
                    ih = fmaxf(ih, 0.0f);
                    // gate: iw<=0 or ih<=0 => inter==0 => iou<=0 (or NaN) => false
                    bool pre = (ci[k] == rcls) & (c > r) & (c < V)
                             & (iw > 0.0f) & (ih > 0.0f);
                    if (__any(pre)) {
                        float inter = iw * ih;
                        float uni = rar + ca[k] - inter;
                        float iou = __fdiv_rn(inter, uni);   // IEEE divide
                        if (pre && iou > 0.5f) {
                            // direct edge earlier-key -> later-key
                            unsigned int e = (rk < ck[k])
                                ? (((unsigned)r << 13) | (unsigned)c)
                                : (((unsigned)c << 13) | (unsigned)r);
                            int idx = atomicAdd(paircnt, 1);
                            if (idx < PAIR_CAP) pairs[idx] = e;
                        }
                    }
                }
            }
        }
    }
    grid.sync();

    // ---- P2: greedy NMS as sparse Jacobi fixpoint (block 0) ----
    // keep_{t+1}[v] = valid[v] & !exists edge u->v with keep_t[u].
    // Edges follow key order (DAG) => round t finalizes dependency-depth <= t;
    // unique fixpoint == the reference's sequential greedy scan.
    {
        __shared__ unsigned long long keep[NWD];
        __shared__ unsigned long long sn[NWD];
        __shared__ int chg;
        if (bid == 0) {
            int V = *Vcnt;
            int E = *paircnt; if (E > PAIR_CAP) E = PAIR_CAP;
            int fullw = V >> 6, rem2 = V & 63;
            unsigned long long vm = 0ULL;
            if (tid < NWD) {
                vm = (tid < fullw) ? ~0ULL
                   : (tid == fullw && rem2) ? ((1ULL << rem2) - 1ULL) : 0ULL;
                keep[tid] = vm;               // K0 = all compacted (valid)
            }
            __syncthreads();
            for (int round = 0; round < 8192; ++round) {
                if (tid < NWD) sn[tid] = 0ULL;
                if (tid == 0) chg = 0;
                __syncthreads();
                for (int e = tid; e < E; e += 256) {
                    unsigned int p = pairs[e];
                    int u = p >> 13, v = p & 8191;
                    if ((keep[u >> 6] >> (u & 63)) & 1ULL)
                        atomicOr(&sn[v >> 6], 1ULL << (v & 63));
                }
                __syncthreads();
                if (tid < NWD) {
                    unsigned long long nk = vm & ~sn[tid];
                    if (nk != keep[tid]) { keep[tid] = nk; chg = 1; }
                }
                __syncthreads();
                if (!chg) break;
            }
            if (tid < NWD) keepw[tid] = keep[tid];
        }
    }
    grid.sync();

    // ---- P3: outputs ----
    if (gid < N) {
        int cm = cmap[gid];
        float m = 0.0f;
        if (cm >= 0) m = (float)((keepw[cm >> 6] >> (cm & 63)) & 1ULL);
        float4 b = ((const float4*)box)[gid];
        out[gid * 5 + 0] = b.x * m;
        out[gid * 5 + 1] = b.y * m;
        out[gid * 5 + 2] = b.z * m;
        out[gid * 5 + 3] = b.w * m;
        out[gid * 5 + 4] = conf[gid] * m;
        out[5 * N + gid] = (float)cls[gid];
        out[6 * N + gid] = m;
    }
}

// ---------------- launch -------------------------------------------------
extern "C" void kernel_launch(void* const* d_in, const int* in_sizes, int n_in,
                              void* d_out, int out_size, void* d_ws, size_t ws_size,
                              hipStream_t stream) {
    const float* box    = (const float*)d_in[0];
    const float* conf   = (const float*)d_in[1];
    const float* logits = (const float*)d_in[2];
    float* out = (float*)d_out;

    char* ws = (char*)d_ws;
    int* cls      = (int*)(ws + 0);                                  // 32 KB
    int* cmap     = (int*)(ws + 32768);                              // 32 KB
    int* Vcnt     = (int*)(ws + 65536);
    int* paircnt  = (int*)(ws + 65600);
    unsigned long long* keepw = (unsigned long long*)(ws + 66560);   // 1 KB
    float* sarea  = (float*)(ws + 98304);                            // 32 KB
    int* scls     = (int*)(ws + 131072);                             // 32 KB
    unsigned long long* skey = (unsigned long long*)(ws + 163840);   // 64 KB
    float4* sbx   = (float4*)(ws + 262144);                          // 128 KB
    unsigned int* pairs = (unsigned int*)(ws + 393216);              // 4 MB

    void* args[] = { (void*)&box, (void*)&conf, (void*)&logits, (void*)&cls,
                     (void*)&cmap, (void*)&sbx, (void*)&sarea, (void*)&scls,
                     (void*)&skey, (void*)&Vcnt, (void*)&paircnt, (void*)&pairs,
                     (void*)&keepw, (void*)&out };
    hipLaunchCooperativeKernel(k_fused, dim3(256), dim3(256), args, 0, stream);
}